// Round 3
// baseline (1764.245 us; speedup 1.0000x reference)
//
#include <hip/hip_runtime.h>
#include <hip/hip_bf16.h>

#define NB 16
#define N2V 618
#define N3V 2466
#define FEAT 963
#define HID 192
#define IN_DIM 1163
#define KPAD 1184          // 1163 padded to multiple of 32
#define MTOT (NB * N3V)    // 39456

typedef __attribute__((ext_vector_type(8))) short bf16x8;
typedef __attribute__((ext_vector_type(4))) float f32x4;

__device__ __forceinline__ float bf2f(ushort u) {
    return __uint_as_float(((unsigned)u) << 16);
}
__device__ __forceinline__ ushort f2bf(float f) {   // round-to-nearest-even
    unsigned u = __float_as_uint(f);
    return (ushort)((u + 0x7FFFu + ((u >> 16) & 1u)) >> 16);
}

// ---------------------------------------------------------------------------
// q,k,v projections: mv grade-1 only -> rows 1..3 of W
// ---------------------------------------------------------------------------
__global__ void qkv_kernel(const float* __restrict__ x2,
                           const float* __restrict__ Wq, const float* __restrict__ bq,
                           const float* __restrict__ Wk, const float* __restrict__ bk,
                           const float* __restrict__ Wv, const float* __restrict__ bv,
                           float* __restrict__ q, float* __restrict__ k, float* __restrict__ v)
{
    int idx = blockIdx.x * 256 + threadIdx.x;
    if (idx >= NB * N2V) return;
    float c0 = x2[idx * 3 + 0], c1 = x2[idx * 3 + 1], c2 = x2[idx * 3 + 2];
#pragma unroll
    for (int d = 0; d < 8; ++d) {
        q[idx * 8 + d] = bq[d] + c0 * Wq[8 + d] + c1 * Wq[16 + d] + c2 * Wq[24 + d];
        k[idx * 8 + d] = bk[d] + c0 * Wk[8 + d] + c1 * Wk[16 + d] + c2 * Wk[24 + d];
        v[idx * 8 + d] = bv[d] + c0 * Wv[8 + d] + c1 * Wv[16 + d] + c2 * Wv[24 + d];
    }
}

// ---------------------------------------------------------------------------
// fused softmax attention: one block per (b,n) row
// ---------------------------------------------------------------------------
__global__ __launch_bounds__(256) void attn_kernel(const float* __restrict__ q,
                                                   const float* __restrict__ k,
                                                   const float* __restrict__ v,
                                                   float* __restrict__ att)
{
    int bn = blockIdx.x;
    int b = bn / N2V;
    int tid = threadIdx.x;
    int lane = tid & 63, wid = tid >> 6;
    __shared__ float red[4][12];
    __shared__ float fin[12];

    float qv[8];
#pragma unroll
    for (int d = 0; d < 8; ++d) qv[d] = q[(size_t)bn * 8 + d];
    const float* kb = k + (size_t)b * N2V * 8;
    const float* vb = v + (size_t)b * N2V * 8;

    const float scale = 0.35355339059327373f;
    float svals[3];
    float mx = -3.0e38f;
    int cnt = 0;
    for (int m = tid; m < N2V; m += 256) {
        const float4 k0 = *(const float4*)(kb + m * 8);
        const float4 k1 = *(const float4*)(kb + m * 8 + 4);
        float s = qv[0] * k0.x + qv[1] * k0.y + qv[2] * k0.z + qv[3] * k0.w
                + qv[4] * k1.x + qv[5] * k1.y + qv[6] * k1.z + qv[7] * k1.w;
        s *= scale;
        svals[cnt++] = s;
        mx = fmaxf(mx, s);
    }
#pragma unroll
    for (int o = 32; o; o >>= 1) mx = fmaxf(mx, __shfl_down(mx, o));
    if (lane == 0) red[wid][0] = mx;
    __syncthreads();
    if (tid == 0)
        fin[0] = fmaxf(fmaxf(red[0][0], red[1][0]), fmaxf(red[2][0], red[3][0]));
    __syncthreads();
    mx = fin[0];

    float sum = 0.f, acc[8];
#pragma unroll
    for (int d = 0; d < 8; ++d) acc[d] = 0.f;
    int i = 0;
    for (int m = tid; m < N2V; m += 256, ++i) {
        float p = __expf(svals[i] - mx);
        sum += p;
        const float4 v0 = *(const float4*)(vb + m * 8);
        const float4 v1 = *(const float4*)(vb + m * 8 + 4);
        acc[0] += p * v0.x; acc[1] += p * v0.y; acc[2] += p * v0.z; acc[3] += p * v0.w;
        acc[4] += p * v1.x; acc[5] += p * v1.y; acc[6] += p * v1.z; acc[7] += p * v1.w;
    }
#pragma unroll
    for (int o = 32; o; o >>= 1) {
        sum += __shfl_down(sum, o);
#pragma unroll
        for (int d = 0; d < 8; ++d) acc[d] += __shfl_down(acc[d], o);
    }
    if (lane == 0) {
        red[wid][0] = sum;
#pragma unroll
        for (int d = 0; d < 8; ++d) red[wid][1 + d] = acc[d];
    }
    __syncthreads();
    if (tid < 9)
        fin[tid] = red[0][tid] + red[1][tid] + red[2][tid] + red[3][tid];
    __syncthreads();
    if (tid < 8)
        att[(size_t)bn * 8 + tid] = fin[1 + tid] / fin[0];
}

// ---------------------------------------------------------------------------
// sparse adjacency extraction (<=6 nnz/row, sorted => deterministic)
// ---------------------------------------------------------------------------
__global__ void adj_extract(const float* __restrict__ adj, int* __restrict__ cols,
                            float* __restrict__ vals)
{
    int m = blockIdx.x;
    __shared__ int cnt;
    __shared__ int lc[8];
    __shared__ float lv[8];
    if (threadIdx.x == 0) cnt = 0;
    __syncthreads();
    for (int c = threadIdx.x; c < N3V; c += 256) {
        float a = adj[(size_t)m * N3V + c];
        if (a != 0.f) {
            int p = atomicAdd(&cnt, 1);
            if (p < 6) { lc[p] = c; lv[p] = a; }
        }
    }
    __syncthreads();
    if (threadIdx.x == 0) {
        int n = cnt < 6 ? cnt : 6;
        for (int i = 1; i < n; ++i) {
            int ci = lc[i]; float vi = lv[i]; int j = i - 1;
            while (j >= 0 && lc[j] > ci) { lc[j + 1] = lc[j]; lv[j + 1] = lv[j]; --j; }
            lc[j + 1] = ci; lv[j + 1] = vi;
        }
        for (int i = 0; i < 6; ++i) {
            cols[m * 6 + i] = (i < n) ? lc[i] : 0;
            vals[m * 6 + i] = (i < n) ? lv[i] : 0.f;
        }
    }
}

// ---------------------------------------------------------------------------
// F[bn][k] bf16: concat(x[963], xh[192], att[8], zeros) padded to KPAD
// ---------------------------------------------------------------------------
__global__ void build_F(const float* __restrict__ x, const float* __restrict__ xh,
                        const float* __restrict__ att, ushort* __restrict__ F)
{
    int bn = blockIdx.x;
    for (int k = threadIdx.x; k < KPAD; k += 256) {
        float v = 0.f;
        if (k < FEAT) v = x[(size_t)bn * FEAT + k];
        else if (k < FEAT + HID) v = xh[(size_t)bn * HID + (k - FEAT)];
        else if (k < IN_DIM) v = att[(size_t)bn * 8 + (k - FEAT - HID)];
        F[(size_t)bn * KPAD + k] = f2bf(v);
    }
}

// ---------------------------------------------------------------------------
// fused-weight transposes: Wt[n][k2], n<192, k2 = [W half | loopW half]
// ---------------------------------------------------------------------------
__global__ void prep_wt_entry(const float* __restrict__ W, const float* __restrict__ L,
                              ushort* __restrict__ Wt)
{
    int idx = blockIdx.x * 256 + threadIdx.x;
    if (idx >= 192 * 2 * KPAD) return;
    int n = idx / (2 * KPAD), k2 = idx % (2 * KPAD);
    float v = 0.f;
    if (k2 < KPAD) { if (k2 < IN_DIM) v = W[k2 * 192 + n]; }
    else { int k = k2 - KPAD; if (k < IN_DIM) v = L[k * 192 + n]; }
    Wt[idx] = f2bf(v);
}

__global__ void prep_wt192(const float* __restrict__ W, const float* __restrict__ L,
                           ushort* __restrict__ Wt)
{
    int idx = blockIdx.x * 256 + threadIdx.x;
    if (idx >= 192 * 384) return;
    int n = idx / 384, k2 = idx % 384;
    float v = (k2 < 192) ? W[k2 * 192 + n] : L[(k2 - 192) * 192 + n];
    Wt[idx] = f2bf(v);
}

// ---------------------------------------------------------------------------
// fused GConv:  out[M,192] = act( [adj@X | X] @ Wt^T + bias )
//   MODE 0: X = h [MTOT,192]          (Kh=192)
//   MODE 1: X = unpooled F rows        (Kh=1184; row r -> 0.5(F[p0]+F[p1]))
// act: 0 = relu ; 1 = 0.5*(hprev + relu(.))
// Block = 256 thr (4 waves); wave w -> rows [lb*64+16w, +16), cols 0..192 (nt=12).
// XCD-chunked bijective swizzle keeps each batch's X slice on one XCD's L2.
// ---------------------------------------------------------------------------
template <int MODE>
__global__ __launch_bounds__(256) void fused_gconv(
    const ushort* __restrict__ X, const int* __restrict__ cols,
    const float* __restrict__ vals, const int* __restrict__ unpool,
    const ushort* __restrict__ Wt, const float* __restrict__ bias,
    const ushort* __restrict__ hprev, ushort* __restrict__ outp,
    int Kh, int actmode)
{
    const int K2 = 2 * Kh;
    // bijective XCD-chunked swizzle (nwg = gridDim.x)
    int nwg = gridDim.x;
    int qq = nwg >> 3, rr8 = nwg & 7;
    int xcd = blockIdx.x & 7, slot = blockIdx.x >> 3;
    int lb = (xcd < rr8) ? xcd * (qq + 1) + slot : rr8 * (qq + 1) + (xcd - rr8) * qq + slot;

    int tid = threadIdx.x;
    int wave = tid >> 6, lane = tid & 63;
    int lr = lane & 15, lkq = lane >> 4;
    int lk = lkq * 8;

    int row = lb * 64 + wave * 16 + lr;
    if (row >= MTOT) row = MTOT - 1;
    int b = row / N3V, n = row % N3V;

    // own-row source (X-half)
    int p0, p1;
    if (MODE == 1) {
        if (n < N2V) { p0 = b * N2V + n; p1 = -1; }
        else {
            int j = n - N2V;
            p0 = b * N2V + unpool[2 * j];
            p1 = b * N2V + unpool[2 * j + 1];
        }
    } else { p0 = row; p1 = -1; }

    // neighbor gather lists (g-half)
    int gi0[6], gi1[6];
    float gw[6];
#pragma unroll
    for (int j = 0; j < 6; ++j) {
        int c = cols[n * 6 + j];
        gw[j] = vals[n * 6 + j];
        if (MODE == 1) {
            if (c < N2V) { gi0[j] = b * N2V + c; gi1[j] = -1; }
            else {
                int jj = c - N2V;
                gi0[j] = b * N2V + unpool[2 * jj];
                gi1[j] = b * N2V + unpool[2 * jj + 1];
            }
        } else { gi0[j] = b * N3V + c; gi1[j] = -1; }
    }

    const int ldX = (MODE == 1) ? KPAD : 192;
    const int Tg = Kh / 32;
    const int Tall = K2 / 32;

    f32x4 acc[12];
#pragma unroll
    for (int nt = 0; nt < 12; ++nt) acc[nt] = (f32x4){0.f, 0.f, 0.f, 0.f};

    for (int t = 0; t < Tall; ++t) {
        int k2 = t * 32 + lk;
        bf16x8 a;
        if (t < Tg) {
            // g-half: weighted 6-neighbor gather
            int kin = k2;
            float af[8];
#pragma unroll
            for (int e = 0; e < 8; ++e) af[e] = 0.f;
#pragma unroll
            for (int j = 0; j < 6; ++j) {
                float w = gw[j];
                if (w != 0.f) {
                    bf16x8 v0 = *(const bf16x8*)(X + (size_t)gi0[j] * ldX + kin);
                    if (MODE == 1) {
                        if (gi1[j] >= 0) {
                            bf16x8 v1 = *(const bf16x8*)(X + (size_t)gi1[j] * ldX + kin);
#pragma unroll
                            for (int e = 0; e < 8; ++e)
                                af[e] += w * 0.5f * (bf2f((ushort)v0[e]) + bf2f((ushort)v1[e]));
                        } else {
#pragma unroll
                            for (int e = 0; e < 8; ++e) af[e] += w * bf2f((ushort)v0[e]);
                        }
                    } else {
#pragma unroll
                        for (int e = 0; e < 8; ++e) af[e] += w * bf2f((ushort)v0[e]);
                    }
                }
            }
#pragma unroll
            for (int e = 0; e < 8; ++e) a[e] = (short)f2bf(af[e]);
        } else {
            // X-half: own row
            int kin = k2 - Kh;
            if (MODE == 1) {
                bf16x8 v0 = *(const bf16x8*)(X + (size_t)p0 * ldX + kin);
                if (p1 >= 0) {
                    bf16x8 v1 = *(const bf16x8*)(X + (size_t)p1 * ldX + kin);
#pragma unroll
                    for (int e = 0; e < 8; ++e)
                        v0[e] = (short)f2bf(0.5f * (bf2f((ushort)v0[e]) + bf2f((ushort)v1[e])));
                }
                a = v0;
            } else {
                a = *(const bf16x8*)(X + (size_t)p0 * ldX + kin);
            }
        }

        bf16x8 bfr[12];
#pragma unroll
        for (int nt = 0; nt < 12; ++nt)
            bfr[nt] = *(const bf16x8*)(Wt + (size_t)(nt * 16 + lr) * K2 + k2);
#pragma unroll
        for (int nt = 0; nt < 12; ++nt)
            acc[nt] = __builtin_amdgcn_mfma_f32_16x16x32_bf16(a, bfr[nt], acc[nt], 0, 0, 0);
    }

    int crow = lkq * 4;   // D: col = lane&15, row = (lane>>4)*4 + r
#pragma unroll
    for (int r = 0; r < 4; ++r) {
        int orow = lb * 64 + wave * 16 + crow + r;
        if (orow < MTOT) {
#pragma unroll
            for (int nt = 0; nt < 12; ++nt) {
                int nn = nt * 16 + lr;
                float s = acc[nt][r] + bias[nn];
                s = fmaxf(s, 0.f);
                if (actmode == 1)
                    s = 0.5f * (bf2f(hprev[(size_t)orow * 192 + nn]) + s);
                outp[(size_t)orow * 192 + nn] = f2bf(s);
            }
        }
    }
}

// ---------------------------------------------------------------------------
// final head (fp32 weights, bf16 activations)
// ---------------------------------------------------------------------------
__global__ void head_a(const ushort* __restrict__ x4, const float* __restrict__ Wg,
                       const float* __restrict__ loopWg, float* __restrict__ t)
{
    int idx = blockIdx.x * 256 + threadIdx.x;
    if (idx >= MTOT * 6) return;
    int bm = idx / 6, c = idx % 6;
    const float* W = (c < 3) ? Wg : loopWg;
    int cc = (c < 3) ? c : c - 3;
    float s = 0.f;
    for (int k = 0; k < 192; ++k) s += bf2f(x4[(size_t)bm * 192 + k]) * W[k * 3 + cc];
    t[idx] = s;
}

__global__ void head_b(const float* __restrict__ t, const int* __restrict__ cols,
                       const float* __restrict__ vals, const float* __restrict__ bg,
                       float* __restrict__ out)
{
    int idx = blockIdx.x * 256 + threadIdx.x;
    if (idx >= MTOT * 3) return;
    int bm = idx / 3, c = idx % 3;
    int b = bm / N3V, m = bm % N3V;
    float s = 0.f;
#pragma unroll
    for (int j = 0; j < 6; ++j)
        s += vals[m * 6 + j] * t[((size_t)b * N3V + cols[m * 6 + j]) * 6 + c];
    s += t[(size_t)bm * 6 + 3 + c] + bg[c];
    out[idx] = s;
}

// ---------------------------------------------------------------------------
extern "C" void kernel_launch(void* const* d_in, const int* in_sizes, int n_in,
                              void* d_out, int out_size, void* d_ws, size_t ws_size,
                              hipStream_t stream)
{
    const float* x        = (const float*)d_in[0];
    const float* x2       = (const float*)d_in[1];
    const float* xh       = (const float*)d_in[2];
    const float* Wq       = (const float*)d_in[3];
    const float* bq       = (const float*)d_in[4];
    const float* Wk       = (const float*)d_in[5];
    const float* bk       = (const float*)d_in[6];
    const float* Wv       = (const float*)d_in[7];
    const float* bv       = (const float*)d_in[8];
    const float* adj      = (const float*)d_in[9];
    const int*   unpool   = (const int*)d_in[10];
    const float* W_in     = (const float*)d_in[11];
    const float* loopW_in = (const float*)d_in[12];
    const float* b_in     = (const float*)d_in[13];
    const float* res_W    = (const float*)d_in[14];
    const float* res_loopW= (const float*)d_in[15];
    const float* res_b    = (const float*)d_in[16];
    const float* W_out    = (const float*)d_in[17];
    const float* loopW_out= (const float*)d_in[18];
    const float* b_out    = (const float*)d_in[19];
    const float* Wg       = (const float*)d_in[20];
    const float* loopWg   = (const float*)d_in[21];
    const float* bg       = (const float*)d_in[22];
    float* out = (float*)d_out;

    char* ws = (char*)d_ws;
    size_t o = 0;
    auto alloc = [&](size_t bytes) { char* p = ws + o; o += (bytes + 255) & ~(size_t)255; return p; };
    float*  q    = (float*)alloc((size_t)NB * N2V * 8 * 4);
    float*  kbuf = (float*)alloc((size_t)NB * N2V * 8 * 4);
    float*  vbuf = (float*)alloc((size_t)NB * N2V * 8 * 4);
    float*  att  = (float*)alloc((size_t)NB * N2V * 8 * 4);
    int*    cols = (int*)alloc((size_t)N3V * 6 * 4);
    float*  vals = (float*)alloc((size_t)N3V * 6 * 4);
    ushort* F    = (ushort*)alloc((size_t)NB * N2V * KPAD * 2);
    ushort* wt_e = (ushort*)alloc((size_t)192 * 2 * KPAD * 2);
    ushort* wt_r = (ushort*)alloc((size_t)13 * 192 * 384 * 2);
    ushort* h    = (ushort*)alloc((size_t)MTOT * 192 * 2);
    ushort* y    = (ushort*)alloc((size_t)MTOT * 192 * 2);
    float*  ts   = (float*)alloc((size_t)MTOT * 6 * 4);
    if (ws_size < o) return;

    qkv_kernel<<<(NB * N2V + 255) / 256, 256, 0, stream>>>(x2, Wq, bq, Wk, bk, Wv, bv, q, kbuf, vbuf);
    attn_kernel<<<NB * N2V, 256, 0, stream>>>(q, kbuf, vbuf, att);
    adj_extract<<<N3V, 256, 0, stream>>>(adj, cols, vals);
    build_F<<<NB * N2V, 256, 0, stream>>>(x, xh, att, F);
    prep_wt_entry<<<(192 * 2 * KPAD + 255) / 256, 256, 0, stream>>>(W_in, loopW_in, wt_e);
    for (int l = 0; l < 12; ++l)
        prep_wt192<<<(192 * 384 + 255) / 256, 256, 0, stream>>>(
            res_W + (size_t)l * 192 * 192, res_loopW + (size_t)l * 192 * 192,
            wt_r + (size_t)l * 192 * 384);
    prep_wt192<<<(192 * 384 + 255) / 256, 256, 0, stream>>>(
        W_out, loopW_out, wt_r + (size_t)12 * 192 * 384);

    int gblk = (MTOT + 63) / 64;   // 617
    fused_gconv<1><<<gblk, 256, 0, stream>>>(F, cols, vals, unpool, wt_e, b_in,
                                             nullptr, h, KPAD, 0);
    for (int i = 0; i < 6; ++i) {
        const float* B0 = res_b + (size_t)(i * 2 + 0) * 192;
        const float* B1 = res_b + (size_t)(i * 2 + 1) * 192;
        fused_gconv<0><<<gblk, 256, 0, stream>>>(h, cols, vals, unpool,
            wt_r + (size_t)(i * 2 + 0) * 192 * 384, B0, nullptr, y, 192, 0);
        fused_gconv<0><<<gblk, 256, 0, stream>>>(y, cols, vals, unpool,
            wt_r + (size_t)(i * 2 + 1) * 192 * 384, B1, h, h, 192, 1);
    }
    fused_gconv<0><<<gblk, 256, 0, stream>>>(h, cols, vals, unpool,
        wt_r + (size_t)12 * 192 * 384, b_out, nullptr, y, 192, 0);

    head_a<<<(MTOT * 6 + 255) / 256, 256, 0, stream>>>(y, Wg, loopWg, ts);
    head_b<<<(MTOT * 3 + 255) / 256, 256, 0, stream>>>(ts, cols, vals, bg, out);
}

// Round 4
// 1160.440 us; speedup vs baseline: 1.5203x; 1.5203x over previous
//
#include <hip/hip_runtime.h>
#include <hip/hip_bf16.h>

#define NB 16
#define N2V 618
#define N3V 2466
#define FEAT 963
#define HID 192
#define IN_DIM 1163
#define KPAD 1184          // 1163 padded to multiple of 32
#define MTOT (NB * N3V)    // 39456
#define M2   (NB * N2V)    // 9888

typedef __attribute__((ext_vector_type(8))) short bf16x8;
typedef __attribute__((ext_vector_type(4))) float f32x4;

__device__ __forceinline__ float bf2f(ushort u) {
    return __uint_as_float(((unsigned)u) << 16);
}
__device__ __forceinline__ ushort f2bf(float f) {   // round-to-nearest-even
    unsigned u = __float_as_uint(f);
    return (ushort)((u + 0x7FFFu + ((u >> 16) & 1u)) >> 16);
}

// ---------------------------------------------------------------------------
// q,k,v projections: mv grade-1 only -> rows 1..3 of W
// ---------------------------------------------------------------------------
__global__ void qkv_kernel(const float* __restrict__ x2,
                           const float* __restrict__ Wq, const float* __restrict__ bq,
                           const float* __restrict__ Wk, const float* __restrict__ bk,
                           const float* __restrict__ Wv, const float* __restrict__ bv,
                           float* __restrict__ q, float* __restrict__ k, float* __restrict__ v)
{
    int idx = blockIdx.x * 256 + threadIdx.x;
    if (idx >= M2) return;
    float c0 = x2[idx * 3 + 0], c1 = x2[idx * 3 + 1], c2 = x2[idx * 3 + 2];
#pragma unroll
    for (int d = 0; d < 8; ++d) {
        q[idx * 8 + d] = bq[d] + c0 * Wq[8 + d] + c1 * Wq[16 + d] + c2 * Wq[24 + d];
        k[idx * 8 + d] = bk[d] + c0 * Wk[8 + d] + c1 * Wk[16 + d] + c2 * Wk[24 + d];
        v[idx * 8 + d] = bv[d] + c0 * Wv[8 + d] + c1 * Wv[16 + d] + c2 * Wv[24 + d];
    }
}

// ---------------------------------------------------------------------------
// fused softmax attention: one block per (b,n) row
// ---------------------------------------------------------------------------
__global__ __launch_bounds__(256) void attn_kernel(const float* __restrict__ q,
                                                   const float* __restrict__ k,
                                                   const float* __restrict__ v,
                                                   float* __restrict__ att)
{
    int bn = blockIdx.x;
    int b = bn / N2V;
    int tid = threadIdx.x;
    int lane = tid & 63, wid = tid >> 6;
    __shared__ float red[4][12];
    __shared__ float fin[12];

    float qv[8];
#pragma unroll
    for (int d = 0; d < 8; ++d) qv[d] = q[(size_t)bn * 8 + d];
    const float* kb = k + (size_t)b * N2V * 8;
    const float* vb = v + (size_t)b * N2V * 8;

    const float scale = 0.35355339059327373f;
    float svals[3];
    float mx = -3.0e38f;
    int cnt = 0;
    for (int m = tid; m < N2V; m += 256) {
        const float4 k0 = *(const float4*)(kb + m * 8);
        const float4 k1 = *(const float4*)(kb + m * 8 + 4);
        float s = qv[0] * k0.x + qv[1] * k0.y + qv[2] * k0.z + qv[3] * k0.w
                + qv[4] * k1.x + qv[5] * k1.y + qv[6] * k1.z + qv[7] * k1.w;
        s *= scale;
        svals[cnt++] = s;
        mx = fmaxf(mx, s);
    }
#pragma unroll
    for (int o = 32; o; o >>= 1) mx = fmaxf(mx, __shfl_down(mx, o));
    if (lane == 0) red[wid][0] = mx;
    __syncthreads();
    if (tid == 0)
        fin[0] = fmaxf(fmaxf(red[0][0], red[1][0]), fmaxf(red[2][0], red[3][0]));
    __syncthreads();
    mx = fin[0];

    float sum = 0.f, acc[8];
#pragma unroll
    for (int d = 0; d < 8; ++d) acc[d] = 0.f;
    int i = 0;
    for (int m = tid; m < N2V; m += 256, ++i) {
        float p = __expf(svals[i] - mx);
        sum += p;
        const float4 v0 = *(const float4*)(vb + m * 8);
        const float4 v1 = *(const float4*)(vb + m * 8 + 4);
        acc[0] += p * v0.x; acc[1] += p * v0.y; acc[2] += p * v0.z; acc[3] += p * v0.w;
        acc[4] += p * v1.x; acc[5] += p * v1.y; acc[6] += p * v1.z; acc[7] += p * v1.w;
    }
#pragma unroll
    for (int o = 32; o; o >>= 1) {
        sum += __shfl_down(sum, o);
#pragma unroll
        for (int d = 0; d < 8; ++d) acc[d] += __shfl_down(acc[d], o);
    }
    if (lane == 0) {
        red[wid][0] = sum;
#pragma unroll
        for (int d = 0; d < 8; ++d) red[wid][1 + d] = acc[d];
    }
    __syncthreads();
    if (tid < 9)
        fin[tid] = red[0][tid] + red[1][tid] + red[2][tid] + red[3][tid];
    __syncthreads();
    if (tid < 8)
        att[(size_t)bn * 8 + tid] = fin[1 + tid] / fin[0];
}

// ---------------------------------------------------------------------------
// adjacency prep: per n3 row, extract <=6 (col,val) sorted, then expand
// through the unpool midpoint into <=12 batch-local F-row gathers (adj@Up),
// plus the self-term parent pair (Up).
// ---------------------------------------------------------------------------
__global__ void adj_prep(const float* __restrict__ adj, const int* __restrict__ unpool,
                         int* __restrict__ cols, float* __restrict__ vals,
                         int* __restrict__ eidx, float* __restrict__ ew,
                         int* __restrict__ sidx)
{
    int m = blockIdx.x;
    __shared__ int cnt;
    __shared__ int lc[8];
    __shared__ float lv[8];
    if (threadIdx.x == 0) cnt = 0;
    __syncthreads();
    for (int c = threadIdx.x; c < N3V; c += 256) {
        float a = adj[(size_t)m * N3V + c];
        if (a != 0.f) {
            int p = atomicAdd(&cnt, 1);
            if (p < 6) { lc[p] = c; lv[p] = a; }
        }
    }
    __syncthreads();
    if (threadIdx.x == 0) {
        int n = cnt < 6 ? cnt : 6;
        for (int i = 1; i < n; ++i) {
            int ci = lc[i]; float vi = lv[i]; int j = i - 1;
            while (j >= 0 && lc[j] > ci) { lc[j + 1] = lc[j]; lv[j + 1] = lv[j]; --j; }
            lc[j + 1] = ci; lv[j + 1] = vi;
        }
        int ne = 0;
        for (int i = 0; i < 6; ++i) {
            int c = (i < n) ? lc[i] : 0;
            float w = (i < n) ? lv[i] : 0.f;
            cols[m * 6 + i] = c;
            vals[m * 6 + i] = w;
            if (i < n) {
                if (c < N2V) { eidx[m * 12 + ne] = c; ew[m * 12 + ne] = w; ++ne; }
                else {
                    int jj = c - N2V;
                    eidx[m * 12 + ne] = unpool[2 * jj];     ew[m * 12 + ne] = 0.5f * w; ++ne;
                    eidx[m * 12 + ne] = unpool[2 * jj + 1]; ew[m * 12 + ne] = 0.5f * w; ++ne;
                }
            }
        }
        for (; ne < 12; ++ne) { eidx[m * 12 + ne] = 0; ew[m * 12 + ne] = 0.f; }
        if (m < N2V) { sidx[m * 2] = m; sidx[m * 2 + 1] = -1; }
        else {
            int j = m - N2V;
            sidx[m * 2] = unpool[2 * j];
            sidx[m * 2 + 1] = unpool[2 * j + 1];
        }
    }
}

// ---------------------------------------------------------------------------
// F[bn][k] bf16: concat(x[963], xh[192], att[8], zeros) padded to KPAD
// ---------------------------------------------------------------------------
__global__ void build_F(const float* __restrict__ x, const float* __restrict__ xh,
                        const float* __restrict__ att, ushort* __restrict__ F)
{
    int bn = blockIdx.x;
    for (int k = threadIdx.x; k < KPAD; k += 256) {
        float v = 0.f;
        if (k < FEAT) v = x[(size_t)bn * FEAT + k];
        else if (k < FEAT + HID) v = xh[(size_t)bn * HID + (k - FEAT)];
        else if (k < IN_DIM) v = att[(size_t)bn * 8 + (k - FEAT - HID)];
        F[(size_t)bn * KPAD + k] = f2bf(v);
    }
}

// ---------------------------------------------------------------------------
// weight transposes: Wt[n][k], fused N = [W cols | loopW cols]
// ---------------------------------------------------------------------------
__global__ void prep_wt_entry(const float* __restrict__ W, const float* __restrict__ L,
                              ushort* __restrict__ Wt)
{
    int idx = blockIdx.x * 256 + threadIdx.x;
    if (idx >= 384 * KPAD) return;
    int n = idx / KPAD, k = idx % KPAD;
    float v = 0.f;
    if (k < IN_DIM) v = (n < 192) ? W[k * 192 + n] : L[k * 192 + (n - 192)];
    Wt[idx] = f2bf(v);
}

// one kernel for all 13 [192,192] layer pairs (12 res + 1 out)
__global__ void prep_wt_res(const float* __restrict__ res_W, const float* __restrict__ res_loopW,
                            const float* __restrict__ W_out, const float* __restrict__ loopW_out,
                            ushort* __restrict__ Wt)
{
    int idx = blockIdx.x * 256 + threadIdx.x;
    if (idx >= 13 * 384 * 192) return;
    int l = idx / (384 * 192);
    int rem = idx % (384 * 192);
    int n = rem / 192, k = rem % 192;
    const float* W = (l < 12) ? (res_W + (size_t)l * 192 * 192) : W_out;
    const float* L = (l < 12) ? (res_loopW + (size_t)l * 192 * 192) : loopW_out;
    float v = (n < 192) ? W[k * 192 + n] : L[k * 192 + (n - 192)];
    Wt[idx] = f2bf(v);
}

// ---------------------------------------------------------------------------
// streaming MFMA GEMM: C[M,384] = A[M,KTILES*32] @ Wt^T   (Wt[384][KTILES*32])
// block = 256 thr (4 waves); block covers 16 rows; wave w -> cols [96w, 96w+96)
// compile-time KTILES -> fully unrolled, software-pipelined by the compiler
// ---------------------------------------------------------------------------
template <int KTILES, int LDA>
__global__ __launch_bounds__(256) void gemm_t(
    const ushort* __restrict__ A, const ushort* __restrict__ Wt,
    ushort* __restrict__ C, int M)
{
    const int KW = KTILES * 32;
    int tid = threadIdx.x;
    int wave = tid >> 6, lane = tid & 63;
    int lr = lane & 15, lkq = lane >> 4, lk = lkq * 8;
    int row = blockIdx.x * 16 + lr;
    if (row >= M) row = M - 1;
    int ncol0 = wave * 96;

    f32x4 acc[6];
#pragma unroll
    for (int nt = 0; nt < 6; ++nt) acc[nt] = (f32x4){0.f, 0.f, 0.f, 0.f};

    auto body = [&](int t) {
        bf16x8 a = *(const bf16x8*)(A + (size_t)row * LDA + t * 32 + lk);
        bf16x8 b[6];
#pragma unroll
        for (int nt = 0; nt < 6; ++nt)
            b[nt] = *(const bf16x8*)(Wt + (size_t)(ncol0 + nt * 16 + lr) * KW + t * 32 + lk);
#pragma unroll
        for (int nt = 0; nt < 6; ++nt)
            acc[nt] = __builtin_amdgcn_mfma_f32_16x16x32_bf16(a, b[nt], acc[nt], 0, 0, 0);
    };
    if constexpr (KTILES <= 12) {
#pragma unroll
        for (int t = 0; t < KTILES; ++t) body(t);
    } else {
#pragma unroll 4
        for (int t = 0; t < KTILES; ++t) body(t);
    }

    int crow = lkq * 4;    // D: col = lane&15, row = (lane>>4)*4 + r
#pragma unroll
    for (int r = 0; r < 4; ++r) {
        int orow = blockIdx.x * 16 + crow + r;
        if (orow < M) {
#pragma unroll
            for (int nt = 0; nt < 6; ++nt)
                C[(size_t)orow * 384 + ncol0 + nt * 16 + lr] = f2bf(acc[nt][r]);
        }
    }
}

// ---------------------------------------------------------------------------
// entry combine: h[b,n3,f] = relu( sum_i ew[n3,i]*Pw[b,eidx[n3,i],f]
//                                 + mid(Pl over sidx) + bias[f] )
// u2[r][0:192] = Pw = F@W_in ; u2[r][192:384] = Pl = F@loopW_in
// ---------------------------------------------------------------------------
__global__ void combine_entry(const ushort* __restrict__ u2, const int* __restrict__ eidx,
                              const float* __restrict__ ew, const int* __restrict__ sidx,
                              const float* __restrict__ bias, ushort* __restrict__ h)
{
    int bm = blockIdx.x;
    int f = threadIdx.x;
    int b = bm / N3V, n = bm % N3V;
    const ushort* base = u2 + (size_t)b * N2V * 384;
    float s = 0.f;
#pragma unroll
    for (int i = 0; i < 12; ++i)
        s += ew[n * 12 + i] * bf2f(base[(size_t)eidx[n * 12 + i] * 384 + f]);
    int p0 = sidx[n * 2], p1 = sidx[n * 2 + 1];
    float sl = bf2f(base[(size_t)p0 * 384 + 192 + f]);
    if (p1 >= 0) sl = 0.5f * (sl + bf2f(base[(size_t)p1 * 384 + 192 + f]));
    s += sl + bias[f];
    h[(size_t)bm * 192 + f] = f2bf(fmaxf(s, 0.f));
}

// ---------------------------------------------------------------------------
// res combine: out = relu(spmv(adj, u[:, :192]) + u[:, 192:] + bias)
// mode 1: out = 0.5*(hprev + relu(.))
// ---------------------------------------------------------------------------
__global__ void combine_res(const ushort* __restrict__ u, const int* __restrict__ cols,
                            const float* __restrict__ vals, const float* __restrict__ bias,
                            const ushort* __restrict__ hprev, ushort* __restrict__ out, int mode)
{
    int bm = blockIdx.x;
    int f = threadIdx.x;
    int b = bm / N3V, m = bm % N3V;
    float s = 0.f;
#pragma unroll
    for (int j = 0; j < 6; ++j) {
        int c = cols[m * 6 + j];
        s += vals[m * 6 + j] * bf2f(u[((size_t)b * N3V + c) * 384 + f]);
    }
    s += bf2f(u[(size_t)bm * 384 + 192 + f]) + bias[f];
    s = fmaxf(s, 0.f);
    if (mode) s = 0.5f * (bf2f(hprev[(size_t)bm * 192 + f]) + s);
    out[(size_t)bm * 192 + f] = f2bf(s);
}

// ---------------------------------------------------------------------------
// final head (fp32 weights, bf16 activations)
// ---------------------------------------------------------------------------
__global__ void head_a(const ushort* __restrict__ x4, const float* __restrict__ Wg,
                       const float* __restrict__ loopWg, float* __restrict__ t)
{
    int idx = blockIdx.x * 256 + threadIdx.x;
    if (idx >= MTOT * 6) return;
    int bm = idx / 6, c = idx % 6;
    const float* W = (c < 3) ? Wg : loopWg;
    int cc = (c < 3) ? c : c - 3;
    float s = 0.f;
    for (int k = 0; k < 192; ++k) s += bf2f(x4[(size_t)bm * 192 + k]) * W[k * 3 + cc];
    t[idx] = s;
}

__global__ void head_b(const float* __restrict__ t, const int* __restrict__ cols,
                       const float* __restrict__ vals, const float* __restrict__ bg,
                       float* __restrict__ out)
{
    int idx = blockIdx.x * 256 + threadIdx.x;
    if (idx >= MTOT * 3) return;
    int bm = idx / 3, c = idx % 3;
    int b = bm / N3V, m = bm % N3V;
    float s = 0.f;
#pragma unroll
    for (int j = 0; j < 6; ++j)
        s += vals[m * 6 + j] * t[((size_t)b * N3V + cols[m * 6 + j]) * 6 + c];
    s += t[(size_t)bm * 6 + 3 + c] + bg[c];
    out[idx] = s;
}

// ---------------------------------------------------------------------------
extern "C" void kernel_launch(void* const* d_in, const int* in_sizes, int n_in,
                              void* d_out, int out_size, void* d_ws, size_t ws_size,
                              hipStream_t stream)
{
    const float* x        = (const float*)d_in[0];
    const float* x2       = (const float*)d_in[1];
    const float* xh       = (const float*)d_in[2];
    const float* Wq       = (const float*)d_in[3];
    const float* bq       = (const float*)d_in[4];
    const float* Wk       = (const float*)d_in[5];
    const float* bk       = (const float*)d_in[6];
    const float* Wv       = (const float*)d_in[7];
    const float* bv       = (const float*)d_in[8];
    const float* adj      = (const float*)d_in[9];
    const int*   unpool   = (const int*)d_in[10];
    const float* W_in     = (const float*)d_in[11];
    const float* loopW_in = (const float*)d_in[12];
    const float* b_in     = (const float*)d_in[13];
    const float* res_W    = (const float*)d_in[14];
    const float* res_loopW= (const float*)d_in[15];
    const float* res_b    = (const float*)d_in[16];
    const float* W_out    = (const float*)d_in[17];
    const float* loopW_out= (const float*)d_in[18];
    const float* b_out    = (const float*)d_in[19];
    const float* Wg       = (const float*)d_in[20];
    const float* loopWg   = (const float*)d_in[21];
    const float* bg       = (const float*)d_in[22];
    float* out = (float*)d_out;

    char* ws = (char*)d_ws;
    size_t o = 0;
    auto alloc = [&](size_t bytes) { char* p = ws + o; o += (bytes + 255) & ~(size_t)255; return p; };
    float*  q    = (float*)alloc((size_t)M2 * 8 * 4);
    float*  kbuf = (float*)alloc((size_t)M2 * 8 * 4);
    float*  vbuf = (float*)alloc((size_t)M2 * 8 * 4);
    float*  att  = (float*)alloc((size_t)M2 * 8 * 4);
    int*    cols = (int*)alloc((size_t)N3V * 6 * 4);
    float*  vals = (float*)alloc((size_t)N3V * 6 * 4);
    int*    eidx = (int*)alloc((size_t)N3V * 12 * 4);
    float*  ewgt = (float*)alloc((size_t)N3V * 12 * 4);
    int*    sidx = (int*)alloc((size_t)N3V * 2 * 4);
    ushort* F    = (ushort*)alloc((size_t)M2 * KPAD * 2);
    ushort* wt_e = (ushort*)alloc((size_t)384 * KPAD * 2);
    ushort* wt_r = (ushort*)alloc((size_t)13 * 384 * 192 * 2);
    ushort* u2   = (ushort*)alloc((size_t)M2 * 384 * 2);
    ushort* u    = (ushort*)alloc((size_t)MTOT * 384 * 2);
    ushort* h    = (ushort*)alloc((size_t)MTOT * 192 * 2);
    ushort* y    = (ushort*)alloc((size_t)MTOT * 192 * 2);
    float*  ts   = (float*)alloc((size_t)MTOT * 6 * 4);
    if (ws_size < o) return;

    qkv_kernel<<<(M2 + 255) / 256, 256, 0, stream>>>(x2, Wq, bq, Wk, bk, Wv, bv, q, kbuf, vbuf);
    attn_kernel<<<M2, 256, 0, stream>>>(q, kbuf, vbuf, att);
    adj_prep<<<N3V, 256, 0, stream>>>(adj, unpool, cols, vals, eidx, ewgt, sidx);
    build_F<<<M2, 256, 0, stream>>>(x, xh, att, F);
    prep_wt_entry<<<(384 * KPAD + 255) / 256, 256, 0, stream>>>(W_in, loopW_in, wt_e);
    prep_wt_res<<<(13 * 384 * 192 + 255) / 256, 256, 0, stream>>>(res_W, res_loopW, W_out, loopW_out, wt_r);

    // entry: u2 = F @ [W_in | loopW_in]   (M = 9888, K = 1184)
    gemm_t<KPAD / 32, KPAD><<<M2 / 16, 256, 0, stream>>>(F, wt_e, u2, M2);
    combine_entry<<<MTOT, 192, 0, stream>>>(u2, eidx, ewgt, sidx, b_in, h);

    for (int i = 0; i < 6; ++i) {
        const float* B0 = res_b + (size_t)(i * 2 + 0) * 192;
        const float* B1 = res_b + (size_t)(i * 2 + 1) * 192;
        gemm_t<6, 192><<<MTOT / 16, 256, 0, stream>>>(h, wt_r + (size_t)(i * 2 + 0) * 384 * 192, u, MTOT);
        combine_res<<<MTOT, 192, 0, stream>>>(u, cols, vals, B0, nullptr, y, 0);
        gemm_t<6, 192><<<MTOT / 16, 256, 0, stream>>>(y, wt_r + (size_t)(i * 2 + 1) * 384 * 192, u, MTOT);
        combine_res<<<MTOT, 192, 0, stream>>>(u, cols, vals, B1, h, h, 1);
    }

    gemm_t<6, 192><<<MTOT / 16, 256, 0, stream>>>(h, wt_r + (size_t)12 * 384 * 192, u, MTOT);
    combine_res<<<MTOT, 192, 0, stream>>>(u, cols, vals, b_out, nullptr, y, 0);

    head_a<<<(MTOT * 6 + 255) / 256, 256, 0, stream>>>(y, Wg, loopWg, ts);
    head_b<<<(MTOT * 3 + 255) / 256, 256, 0, stream>>>(ts, cols, vals, bg, out);
}

// Round 5
// 814.812 us; speedup vs baseline: 2.1652x; 1.4242x over previous
//
#include <hip/hip_runtime.h>
#include <hip/hip_bf16.h>

#define NB 16
#define N2V 618
#define N3V 2466
#define FEAT 963
#define HID 192
#define IN_DIM 1163
#define KPAD2 1216         // 1163 padded to 38*32 (even tile count for 2-deep pipeline)
#define ETILES 38
#define MTOT (NB * N3V)    // 39456
#define M2   (NB * N2V)    // 9888

typedef __attribute__((ext_vector_type(8))) short bf16x8;
typedef __attribute__((ext_vector_type(4))) float f32x4;

__device__ __forceinline__ float bf2f(ushort u) {
    return __uint_as_float(((unsigned)u) << 16);
}
__device__ __forceinline__ ushort f2bf(float f) {   // round-to-nearest-even
    unsigned u = __float_as_uint(f);
    return (ushort)((u + 0x7FFFu + ((u >> 16) & 1u)) >> 16);
}
// bijective XCD-chunk swizzle (m204)
__device__ __forceinline__ int xcd_swz(int bid, int G) {
    int q = G >> 3, r = G & 7;
    int xcd = bid & 7, slot = bid >> 3;
    return (xcd < r) ? xcd * (q + 1) + slot : r * (q + 1) + (xcd - r) * q + slot;
}

// ---------------------------------------------------------------------------
// q,k,v projections: mv grade-1 only -> rows 1..3 of W
// ---------------------------------------------------------------------------
__global__ void qkv_kernel(const float* __restrict__ x2,
                           const float* __restrict__ Wq, const float* __restrict__ bq,
                           const float* __restrict__ Wk, const float* __restrict__ bk,
                           const float* __restrict__ Wv, const float* __restrict__ bv,
                           float* __restrict__ q, float* __restrict__ k, float* __restrict__ v)
{
    int idx = blockIdx.x * 256 + threadIdx.x;
    if (idx >= M2) return;
    float c0 = x2[idx * 3 + 0], c1 = x2[idx * 3 + 1], c2 = x2[idx * 3 + 2];
#pragma unroll
    for (int d = 0; d < 8; ++d) {
        q[idx * 8 + d] = bq[d] + c0 * Wq[8 + d] + c1 * Wq[16 + d] + c2 * Wq[24 + d];
        k[idx * 8 + d] = bk[d] + c0 * Wk[8 + d] + c1 * Wk[16 + d] + c2 * Wk[24 + d];
        v[idx * 8 + d] = bv[d] + c0 * Wv[8 + d] + c1 * Wv[16 + d] + c2 * Wv[24 + d];
    }
}

// ---------------------------------------------------------------------------
// fused softmax attention: one block per (b,n) row
// ---------------------------------------------------------------------------
__global__ __launch_bounds__(256) void attn_kernel(const float* __restrict__ q,
                                                   const float* __restrict__ k,
                                                   const float* __restrict__ v,
                                                   float* __restrict__ att)
{
    int bn = blockIdx.x;
    int b = bn / N2V;
    int tid = threadIdx.x;
    int lane = tid & 63, wid = tid >> 6;
    __shared__ float red[4][12];
    __shared__ float fin[12];

    float qv[8];
#pragma unroll
    for (int d = 0; d < 8; ++d) qv[d] = q[(size_t)bn * 8 + d];
    const float* kb = k + (size_t)b * N2V * 8;
    const float* vb = v + (size_t)b * N2V * 8;

    const float scale = 0.35355339059327373f;
    float svals[3];
    float mx = -3.0e38f;
    int cnt = 0;
    for (int m = tid; m < N2V; m += 256) {
        const float4 k0 = *(const float4*)(kb + m * 8);
        const float4 k1 = *(const float4*)(kb + m * 8 + 4);
        float s = qv[0] * k0.x + qv[1] * k0.y + qv[2] * k0.z + qv[3] * k0.w
                + qv[4] * k1.x + qv[5] * k1.y + qv[6] * k1.z + qv[7] * k1.w;
        s *= scale;
        svals[cnt++] = s;
        mx = fmaxf(mx, s);
    }
#pragma unroll
    for (int o = 32; o; o >>= 1) mx = fmaxf(mx, __shfl_down(mx, o));
    if (lane == 0) red[wid][0] = mx;
    __syncthreads();
    if (tid == 0)
        fin[0] = fmaxf(fmaxf(red[0][0], red[1][0]), fmaxf(red[2][0], red[3][0]));
    __syncthreads();
    mx = fin[0];

    float sum = 0.f, acc[8];
#pragma unroll
    for (int d = 0; d < 8; ++d) acc[d] = 0.f;
    int i = 0;
    for (int m = tid; m < N2V; m += 256, ++i) {
        float p = __expf(svals[i] - mx);
        sum += p;
        const float4 v0 = *(const float4*)(vb + m * 8);
        const float4 v1 = *(const float4*)(vb + m * 8 + 4);
        acc[0] += p * v0.x; acc[1] += p * v0.y; acc[2] += p * v0.z; acc[3] += p * v0.w;
        acc[4] += p * v1.x; acc[5] += p * v1.y; acc[6] += p * v1.z; acc[7] += p * v1.w;
    }
#pragma unroll
    for (int o = 32; o; o >>= 1) {
        sum += __shfl_down(sum, o);
#pragma unroll
        for (int d = 0; d < 8; ++d) acc[d] += __shfl_down(acc[d], o);
    }
    if (lane == 0) {
        red[wid][0] = sum;
#pragma unroll
        for (int d = 0; d < 8; ++d) red[wid][1 + d] = acc[d];
    }
    __syncthreads();
    if (tid < 9)
        fin[tid] = red[0][tid] + red[1][tid] + red[2][tid] + red[3][tid];
    __syncthreads();
    if (tid < 8)
        att[(size_t)bn * 8 + tid] = fin[1 + tid] / fin[0];
}

// ---------------------------------------------------------------------------
// adjacency prep: <=6 (col,val) per row (sorted), plus entry-layer expansion
// through the unpool midpoints (adj@Up, <=12 gathers) and self parent pair.
// ---------------------------------------------------------------------------
__global__ void adj_prep(const float* __restrict__ adj, const int* __restrict__ unpool,
                         int* __restrict__ cols, float* __restrict__ vals,
                         int* __restrict__ eidx, float* __restrict__ ew,
                         int* __restrict__ sidx)
{
    int m = blockIdx.x;
    __shared__ int cnt;
    __shared__ int lc[8];
    __shared__ float lv[8];
    if (threadIdx.x == 0) cnt = 0;
    __syncthreads();
    for (int c = threadIdx.x; c < N3V; c += 256) {
        float a = adj[(size_t)m * N3V + c];
        if (a != 0.f) {
            int p = atomicAdd(&cnt, 1);
            if (p < 6) { lc[p] = c; lv[p] = a; }
        }
    }
    __syncthreads();
    if (threadIdx.x == 0) {
        int n = cnt < 6 ? cnt : 6;
        for (int i = 1; i < n; ++i) {
            int ci = lc[i]; float vi = lv[i]; int j = i - 1;
            while (j >= 0 && lc[j] > ci) { lc[j + 1] = lc[j]; lv[j + 1] = lv[j]; --j; }
            lc[j + 1] = ci; lv[j + 1] = vi;
        }
        int ne = 0;
        for (int i = 0; i < 6; ++i) {
            int c = (i < n) ? lc[i] : 0;
            float w = (i < n) ? lv[i] : 0.f;
            cols[m * 6 + i] = c;
            vals[m * 6 + i] = w;
            if (i < n) {
                if (c < N2V) { eidx[m * 12 + ne] = c; ew[m * 12 + ne] = w; ++ne; }
                else {
                    int jj = c - N2V;
                    eidx[m * 12 + ne] = unpool[2 * jj];     ew[m * 12 + ne] = 0.5f * w; ++ne;
                    eidx[m * 12 + ne] = unpool[2 * jj + 1]; ew[m * 12 + ne] = 0.5f * w; ++ne;
                }
            }
        }
        for (; ne < 12; ++ne) { eidx[m * 12 + ne] = 0; ew[m * 12 + ne] = 0.f; }
        if (m < N2V) { sidx[m * 2] = m; sidx[m * 2 + 1] = -1; }
        else {
            int j = m - N2V;
            sidx[m * 2] = unpool[2 * j];
            sidx[m * 2 + 1] = unpool[2 * j + 1];
        }
    }
}

// ---------------------------------------------------------------------------
// F[bn][k] bf16: concat(x[963], xh[192], att[8], zeros) padded to KPAD2
// ---------------------------------------------------------------------------
__global__ void build_F(const float* __restrict__ x, const float* __restrict__ xh,
                        const float* __restrict__ att, ushort* __restrict__ F)
{
    int bn = blockIdx.x;
    for (int k = threadIdx.x; k < KPAD2; k += 256) {
        float v = 0.f;
        if (k < FEAT) v = x[(size_t)bn * FEAT + k];
        else if (k < FEAT + HID) v = xh[(size_t)bn * HID + (k - FEAT)];
        else if (k < IN_DIM) v = att[(size_t)bn * 8 + (k - FEAT - HID)];
        F[(size_t)bn * KPAD2 + k] = f2bf(v);
    }
}

// ---------------------------------------------------------------------------
// entry weights: Wt[n][k], N = [W cols | loopW cols] (384), K = KPAD2
// ---------------------------------------------------------------------------
__global__ void prep_wt_entry(const float* __restrict__ W, const float* __restrict__ L,
                              ushort* __restrict__ Wt)
{
    int idx = blockIdx.x * 256 + threadIdx.x;
    if (idx >= 384 * KPAD2) return;
    int n = idx / KPAD2, k = idx % KPAD2;
    float v = 0.f;
    if (k < IN_DIM) v = (n < 192) ? W[k * 192 + n] : L[k * 192 + (n - 192)];
    Wt[idx] = f2bf(v);
}

// res/out weights: Wt[n][k2], n<192, k2 = [W k | loopW k] (384); 13 layers
__global__ void prep_wt_res(const float* __restrict__ res_W, const float* __restrict__ res_loopW,
                            const float* __restrict__ W_out, const float* __restrict__ loopW_out,
                            ushort* __restrict__ Wt)
{
    int idx = blockIdx.x * 256 + threadIdx.x;
    if (idx >= 13 * 192 * 384) return;
    int l = idx / (192 * 384);
    int rem = idx % (192 * 384);
    int n = rem / 384, k2 = rem % 384;
    const float* W = (l < 12) ? (res_W + (size_t)l * 192 * 192) : W_out;
    const float* L = (l < 12) ? (res_loopW + (size_t)l * 192 * 192) : loopW_out;
    float v = (k2 < 192) ? W[k2 * 192 + n] : L[(k2 - 192) * 192 + n];
    Wt[idx] = f2bf(v);
}

// ---------------------------------------------------------------------------
// entry GEMM: u2[M2,384] = F[M2,KPAD2] @ Wt^T. 512 thr (8 waves), 64-row block,
// wave w -> cols [48w,48w+48). Explicit 2-deep register double-buffer pipeline.
// ---------------------------------------------------------------------------
__global__ __launch_bounds__(512) void gemm_entry(
    const ushort* __restrict__ F, const ushort* __restrict__ Wt,
    ushort* __restrict__ u2)
{
    int tid = threadIdx.x;
    int wave = tid >> 6, lane = tid & 63;
    int lr = lane & 15, lkq = lane >> 4, lk = lkq * 8;
    int row0 = blockIdx.x * 64;
    int nb = wave * 48;

    int rows[4];
#pragma unroll
    for (int mt = 0; mt < 4; ++mt) {
        int r = row0 + mt * 16 + lr;
        rows[mt] = (r < M2) ? r : M2 - 1;
    }

    f32x4 acc[4][3];
#pragma unroll
    for (int mt = 0; mt < 4; ++mt)
#pragma unroll
        for (int nt = 0; nt < 3; ++nt) acc[mt][nt] = (f32x4){0.f, 0.f, 0.f, 0.f};

    bf16x8 a0[4], b0[3], a1[4], b1[3];
    auto LD = [&](int t, bf16x8 (&a)[4], bf16x8 (&b)[3]) {
#pragma unroll
        for (int mt = 0; mt < 4; ++mt)
            a[mt] = *(const bf16x8*)(F + (size_t)rows[mt] * KPAD2 + t * 32 + lk);
#pragma unroll
        for (int nt = 0; nt < 3; ++nt)
            b[nt] = *(const bf16x8*)(Wt + (size_t)(nb + nt * 16 + lr) * KPAD2 + t * 32 + lk);
    };
    auto MM = [&](bf16x8 (&a)[4], bf16x8 (&b)[3]) {
#pragma unroll
        for (int mt = 0; mt < 4; ++mt)
#pragma unroll
            for (int nt = 0; nt < 3; ++nt)
                acc[mt][nt] = __builtin_amdgcn_mfma_f32_16x16x32_bf16(a[mt], b[nt], acc[mt][nt], 0, 0, 0);
    };

    LD(0, a0, b0);
    for (int t = 0; t < ETILES; t += 2) {
        if (t + 1 < ETILES) LD(t + 1, a1, b1);
        MM(a0, b0);
        if (t + 2 < ETILES) LD(t + 2, a0, b0);
        if (t + 1 < ETILES) MM(a1, b1);
    }

    int crow = lkq * 4;
#pragma unroll
    for (int mt = 0; mt < 4; ++mt)
#pragma unroll
        for (int r = 0; r < 4; ++r) {
            int orow = row0 + mt * 16 + crow + r;
            if (orow < M2) {
#pragma unroll
                for (int nt = 0; nt < 3; ++nt)
                    u2[(size_t)orow * 384 + nb + nt * 16 + lr] = f2bf(acc[mt][nt][r]);
            }
        }
}

// ---------------------------------------------------------------------------
// entry combine: h = relu( sum_i ew*Pw[eidx] + mid(Pl over sidx) + bias )
// 192 thr = 8 rows x 24 col-groups of 8 (16B vector loads). XCD-swizzled.
// ---------------------------------------------------------------------------
__global__ void combine_entry(const ushort* __restrict__ u2, const int* __restrict__ eidx,
                              const float* __restrict__ ew, const int* __restrict__ sidx,
                              const float* __restrict__ bias, ushort* __restrict__ h)
{
    int lb = xcd_swz(blockIdx.x, gridDim.x);
    int tid = threadIdx.x;
    int rloc = tid / 24, f8 = tid % 24;
    int bm = lb * 8 + rloc;
    if (bm >= MTOT) return;
    int b = bm / N3V, n = bm % N3V;
    const ushort* base = u2 + (size_t)b * N2V * 384;

    float acc[8];
#pragma unroll
    for (int e = 0; e < 8; ++e) acc[e] = 0.f;
#pragma unroll
    for (int i = 0; i < 12; ++i) {
        float w = ew[n * 12 + i];
        if (w != 0.f) {
            bf16x8 v = *(const bf16x8*)(base + (size_t)eidx[n * 12 + i] * 384 + f8 * 8);
#pragma unroll
            for (int e = 0; e < 8; ++e) acc[e] += w * bf2f((ushort)v[e]);
        }
    }
    int p0 = sidx[n * 2], p1 = sidx[n * 2 + 1];
    bf16x8 s0 = *(const bf16x8*)(base + (size_t)p0 * 384 + 192 + f8 * 8);
    if (p1 >= 0) {
        bf16x8 s1 = *(const bf16x8*)(base + (size_t)p1 * 384 + 192 + f8 * 8);
#pragma unroll
        for (int e = 0; e < 8; ++e) acc[e] += 0.5f * (bf2f((ushort)s0[e]) + bf2f((ushort)s1[e]));
    } else {
#pragma unroll
        for (int e = 0; e < 8; ++e) acc[e] += bf2f((ushort)s0[e]);
    }
    bf16x8 o;
#pragma unroll
    for (int e = 0; e < 8; ++e)
        o[e] = (short)f2bf(fmaxf(acc[e] + bias[f8 * 8 + e], 0.f));
    *(bf16x8*)(h + (size_t)bm * 192 + f8 * 8) = o;
}

// ---------------------------------------------------------------------------
// spmv: g = adj @ h   (6-point gather-average, 16B vector loads)
// 192 thr = 8 rows x 24 col-groups. XCD-swizzled for per-batch L2 locality.
// ---------------------------------------------------------------------------
__global__ void spmv_g(const ushort* __restrict__ h, const int* __restrict__ cols,
                       const float* __restrict__ vals, ushort* __restrict__ g)
{
    int lb = xcd_swz(blockIdx.x, gridDim.x);
    int tid = threadIdx.x;
    int rloc = tid / 24, f8 = tid % 24;
    int bm = lb * 8 + rloc;
    if (bm >= MTOT) return;
    int b = bm / N3V, m = bm % N3V;
    const ushort* hb = h + (size_t)b * N3V * 192;

    float acc[8];
#pragma unroll
    for (int e = 0; e < 8; ++e) acc[e] = 0.f;
#pragma unroll
    for (int j = 0; j < 6; ++j) {
        float w = vals[m * 6 + j];
        if (w != 0.f) {
            bf16x8 v = *(const bf16x8*)(hb + (size_t)cols[m * 6 + j] * 192 + f8 * 8);
#pragma unroll
            for (int e = 0; e < 8; ++e) acc[e] += w * bf2f((ushort)v[e]);
        }
    }
    bf16x8 o;
#pragma unroll
    for (int e = 0; e < 8; ++e) o[e] = (short)f2bf(acc[e]);
    *(bf16x8*)(g + (size_t)bm * 192 + f8 * 8) = o;
}

// ---------------------------------------------------------------------------
// fused res GConv GEMM: out = act( [g|h] @ Wt^T + bias )
// ACT 0: relu; ACT 1: 0.5*(hprev + relu(.))
// 256 thr (4 waves), 64-row block, wave w -> cols [48w,48w+48). K = 384 (12 tiles,
// first 6 from g, last 6 from selfX). Explicit 2-deep register pipeline.
// ---------------------------------------------------------------------------
template <int ACT>
__global__ __launch_bounds__(256) void gconv_res(
    const ushort* __restrict__ g, const ushort* __restrict__ sx,
    const ushort* __restrict__ Wt, const float* __restrict__ bias,
    const ushort* __restrict__ hprev, ushort* __restrict__ outp)
{
    int tid = threadIdx.x;
    int wave = tid >> 6, lane = tid & 63;
    int lr = lane & 15, lkq = lane >> 4, lk = lkq * 8;
    int row0 = blockIdx.x * 64;
    int nb = wave * 48;

    int rows[4];
#pragma unroll
    for (int mt = 0; mt < 4; ++mt) {
        int r = row0 + mt * 16 + lr;
        rows[mt] = (r < MTOT) ? r : MTOT - 1;
    }

    f32x4 acc[4][3];
#pragma unroll
    for (int mt = 0; mt < 4; ++mt)
#pragma unroll
        for (int nt = 0; nt < 3; ++nt) acc[mt][nt] = (f32x4){0.f, 0.f, 0.f, 0.f};

    bf16x8 a0[4], b0[3], a1[4], b1[3];
    auto LD = [&](int t, bf16x8 (&a)[4], bf16x8 (&b)[3]) {
        const ushort* src = (t < 6) ? g : sx;
        int kk = (t < 6) ? t * 32 : (t - 6) * 32;
#pragma unroll
        for (int mt = 0; mt < 4; ++mt)
            a[mt] = *(const bf16x8*)(src + (size_t)rows[mt] * 192 + kk + lk);
#pragma unroll
        for (int nt = 0; nt < 3; ++nt)
            b[nt] = *(const bf16x8*)(Wt + (size_t)(nb + nt * 16 + lr) * 384 + t * 32 + lk);
    };
    auto MM = [&](bf16x8 (&a)[4], bf16x8 (&b)[3]) {
#pragma unroll
        for (int mt = 0; mt < 4; ++mt)
#pragma unroll
            for (int nt = 0; nt < 3; ++nt)
                acc[mt][nt] = __builtin_amdgcn_mfma_f32_16x16x32_bf16(a[mt], b[nt], acc[mt][nt], 0, 0, 0);
    };

    LD(0, a0, b0);
#pragma unroll
    for (int t = 0; t < 12; t += 2) {
        if (t + 1 < 12) LD(t + 1, a1, b1);
        MM(a0, b0);
        if (t + 2 < 12) LD(t + 2, a0, b0);
        if (t + 1 < 12) MM(a1, b1);
    }

    int crow = lkq * 4;
#pragma unroll
    for (int mt = 0; mt < 4; ++mt)
#pragma unroll
        for (int r = 0; r < 4; ++r) {
            int orow = row0 + mt * 16 + crow + r;
            if (orow < MTOT) {
#pragma unroll
                for (int nt = 0; nt < 3; ++nt) {
                    int nn = nb + nt * 16 + lr;
                    float s = acc[mt][nt][r] + bias[nn];
                    s = fmaxf(s, 0.f);
                    if (ACT) s = 0.5f * (bf2f(hprev[(size_t)orow * 192 + nn]) + s);
                    outp[(size_t)orow * 192 + nn] = f2bf(s);
                }
            }
        }
}

// ---------------------------------------------------------------------------
// final head: t[bm][0:3] = y@Wg, t[bm][3:6] = y@loopWg (one thread per row)
// ---------------------------------------------------------------------------
__global__ void head_a2(const ushort* __restrict__ y, const float* __restrict__ Wg,
                        const float* __restrict__ loopWg, float* __restrict__ t)
{
    int bm = blockIdx.x * 256 + threadIdx.x;
    if (bm >= MTOT) return;
    float s[6];
#pragma unroll
    for (int c = 0; c < 6; ++c) s[c] = 0.f;
    for (int kk = 0; kk < 24; ++kk) {
        bf16x8 v = *(const bf16x8*)(y + (size_t)bm * 192 + kk * 8);
#pragma unroll
        for (int e = 0; e < 8; ++e) {
            float f = bf2f((ushort)v[e]);
            int k = kk * 8 + e;
            s[0] += f * Wg[k * 3 + 0];
            s[1] += f * Wg[k * 3 + 1];
            s[2] += f * Wg[k * 3 + 2];
            s[3] += f * loopWg[k * 3 + 0];
            s[4] += f * loopWg[k * 3 + 1];
            s[5] += f * loopWg[k * 3 + 2];
        }
    }
#pragma unroll
    for (int c = 0; c < 6; ++c) t[(size_t)bm * 6 + c] = s[c];
}

__global__ void head_b(const float* __restrict__ t, const int* __restrict__ cols,
                       const float* __restrict__ vals, const float* __restrict__ bg,
                       float* __restrict__ out)
{
    int idx = blockIdx.x * 256 + threadIdx.x;
    if (idx >= MTOT * 3) return;
    int bm = idx / 3, c = idx % 3;
    int b = bm / N3V, m = bm % N3V;
    float s = 0.f;
#pragma unroll
    for (int j = 0; j < 6; ++j)
        s += vals[m * 6 + j] * t[((size_t)b * N3V + cols[m * 6 + j]) * 6 + c];
    s += t[(size_t)bm * 6 + 3 + c] + bg[c];
    out[idx] = s;
}

// ---------------------------------------------------------------------------
extern "C" void kernel_launch(void* const* d_in, const int* in_sizes, int n_in,
                              void* d_out, int out_size, void* d_ws, size_t ws_size,
                              hipStream_t stream)
{
    const float* x        = (const float*)d_in[0];
    const float* x2       = (const float*)d_in[1];
    const float* xh       = (const float*)d_in[2];
    const float* Wq       = (const float*)d_in[3];
    const float* bq       = (const float*)d_in[4];
    const float* Wk       = (const float*)d_in[5];
    const float* bk       = (const float*)d_in[6];
    const float* Wv       = (const float*)d_in[7];
    const float* bv       = (const float*)d_in[8];
    const float* adj      = (const float*)d_in[9];
    const int*   unpool   = (const int*)d_in[10];
    const float* W_in     = (const float*)d_in[11];
    const float* loopW_in = (const float*)d_in[12];
    const float* b_in     = (const float*)d_in[13];
    const float* res_W    = (const float*)d_in[14];
    const float* res_loopW= (const float*)d_in[15];
    const float* res_b    = (const float*)d_in[16];
    const float* W_out    = (const float*)d_in[17];
    const float* loopW_out= (const float*)d_in[18];
    const float* b_out    = (const float*)d_in[19];
    const float* Wg       = (const float*)d_in[20];
    const float* loopWg   = (const float*)d_in[21];
    const float* bg       = (const float*)d_in[22];
    float* out = (float*)d_out;

    char* ws = (char*)d_ws;
    size_t o = 0;
    auto alloc = [&](size_t bytes) { char* p = ws + o; o += (bytes + 255) & ~(size_t)255; return p; };
    float*  q    = (float*)alloc((size_t)M2 * 8 * 4);
    float*  kbuf = (float*)alloc((size_t)M2 * 8 * 4);
    float*  vbuf = (float*)alloc((size_t)M2 * 8 * 4);
    float*  att  = (float*)alloc((size_t)M2 * 8 * 4);
    int*    cols = (int*)alloc((size_t)N3V * 6 * 4);
    float*  vals = (float*)alloc((size_t)N3V * 6 * 4);
    int*    eidx = (int*)alloc((size_t)N3V * 12 * 4);
    float*  ewgt = (float*)alloc((size_t)N3V * 12 * 4);
    int*    sidx = (int*)alloc((size_t)N3V * 2 * 4);
    ushort* F    = (ushort*)alloc((size_t)M2 * KPAD2 * 2);
    ushort* wt_e = (ushort*)alloc((size_t)384 * KPAD2 * 2);
    ushort* wt_r = (ushort*)alloc((size_t)13 * 192 * 384 * 2);
    ushort* u2   = (ushort*)alloc((size_t)M2 * 384 * 2);
    ushort* g    = (ushort*)alloc((size_t)MTOT * 192 * 2);
    ushort* h    = (ushort*)alloc((size_t)MTOT * 192 * 2);
    ushort* h2   = (ushort*)alloc((size_t)MTOT * 192 * 2);
    ushort* y    = (ushort*)alloc((size_t)MTOT * 192 * 2);
    float*  ts   = (float*)alloc((size_t)MTOT * 6 * 4);
    if (ws_size < o) return;

    qkv_kernel<<<(M2 + 255) / 256, 256, 0, stream>>>(x2, Wq, bq, Wk, bk, Wv, bv, q, kbuf, vbuf);
    attn_kernel<<<M2, 256, 0, stream>>>(q, kbuf, vbuf, att);
    adj_prep<<<N3V, 256, 0, stream>>>(adj, unpool, cols, vals, eidx, ewgt, sidx);
    build_F<<<M2, 256, 0, stream>>>(x, xh, att, F);
    prep_wt_entry<<<(384 * KPAD2 + 255) / 256, 256, 0, stream>>>(W_in, loopW_in, wt_e);
    prep_wt_res<<<(13 * 192 * 384 + 255) / 256, 256, 0, stream>>>(res_W, res_loopW, W_out, loopW_out, wt_r);

    // entry: u2 = F @ [W_in | loopW_in]   (M=9888, K=1216)
    gemm_entry<<<(M2 + 63) / 64, 512, 0, stream>>>(F, wt_e, u2);
    combine_entry<<<(MTOT + 7) / 8, 192, 0, stream>>>(u2, eidx, ewgt, sidx, b_in, h);

    int gg = (MTOT + 63) / 64;       // 617
    int gs = (MTOT + 7) / 8;         // 4932
    ushort* cur = h;
    ushort* nxt = h2;
    for (int i = 0; i < 6; ++i) {
        const float* B0 = res_b + (size_t)(i * 2 + 0) * 192;
        const float* B1 = res_b + (size_t)(i * 2 + 1) * 192;
        const ushort* W0 = wt_r + (size_t)(i * 2 + 0) * 192 * 384;
        const ushort* W1 = wt_r + (size_t)(i * 2 + 1) * 192 * 384;
        spmv_g<<<gs, 192, 0, stream>>>(cur, cols, vals, g);
        gconv_res<0><<<gg, 256, 0, stream>>>(g, cur, W0, B0, nullptr, y);
        spmv_g<<<gs, 192, 0, stream>>>(y, cols, vals, g);
        gconv_res<1><<<gg, 256, 0, stream>>>(g, y, W1, B1, cur, nxt);
        ushort* tmp = cur; cur = nxt; nxt = tmp;
    }

    // out conv (relu)
    spmv_g<<<gs, 192, 0, stream>>>(cur, cols, vals, g);
    gconv_res<0><<<gg, 256, 0, stream>>>(g, cur, wt_r + (size_t)12 * 192 * 384, b_out, nullptr, y);

    head_a2<<<(MTOT + 255) / 256, 256, 0, stream>>>(y, Wg, loopWg, ts);
    head_b<<<(MTOT * 3 + 255) / 256, 256, 0, stream>>>(ts, cols, vals, bg, out);
}